// Round 5
// baseline (299.636 us; speedup 1.0000x reference)
//
#include <hip/hip_runtime.h>
#include <hip/hip_bf16.h>

// Performer (FAVOR+) attention. B=4 H=8 N=4096 D=64 M=256.
// Round-5:
//  - kside: V staged via wave shfl-transpose (2 b64 writes/thread/chunk vs 16
//    conflicted scalar writes); sPhi 16B-granule XOR swizzle (kills 8-way read
//    conflict); grid.x 16->32 (4 blocks/CU resident); Bp frags from pre-split
//    projH/projL.
//  - fixup: tiled LDS transpose, coalesced both sides (was uncoalesced u16
//    scatter at 32 blocks); ksum finalize split to tiny ksfin kernel; ctxsum
//    via atomics.
//  - prep/vsum/out kept verbatim from round 4 (validated).

typedef __attribute__((ext_vector_type(8))) short short8;
typedef __attribute__((ext_vector_type(4))) float floatx4;

constexpr int BB = 4, HH = 8, NN = 4096, DD = 64, MM = 256, BH = 32;
constexpr float SCALE = 0.3535533905932738f;  // 64^-0.25
constexpr float RATIO = 0.0625f;              // 256^-0.5
constexpr float EPSI  = 1e-4f;
constexpr float NEGINF = -3.4e38f;

__device__ inline unsigned pk2(float a, float b) {
  unsigned ua = __float_as_uint(a) + 0x8000u;
  unsigned ub = __float_as_uint(b) + 0x8000u;
  return (ua >> 16) | (ub & 0xffff0000u);
}
__device__ inline float hif(float x) {
  return __uint_as_float((__float_as_uint(x) + 0x8000u) & 0xffff0000u);
}
__device__ inline unsigned short bhi(float x) {
  return (unsigned short)((__float_as_uint(x) + 0x8000u) >> 16);
}
// XOR swizzle of 16B-granule index within 8-granule groups: bijective, makes
// bank-quad = (i + i>>3) & 7 so consecutive i cover all 8 quads.
__device__ inline int ph16(int i) { return (i & 56) | ((i + (i >> 3)) & 7); }

union Frag { short8 s8; unsigned u[4]; };

__device__ inline void atomicMaxF(float* a, float v) {
  unsigned* ai = (unsigned*)a;
  unsigned old = __atomic_load_n(ai, __ATOMIC_RELAXED);
  while (__uint_as_float(old) < v) {
    unsigned assumed = old;
    old = atomicCAS(ai, assumed, __float_as_uint(v));
    if (old == assumed) break;
  }
}

// ---------------- prep: split proj to bf16 planes; init stabk --------------
__global__ __launch_bounds__(256) void prep_kernel(
    const float* __restrict__ proj, unsigned short* __restrict__ projH,
    unsigned short* __restrict__ projL, float* __restrict__ stabk) {
  const int i = blockIdx.x * 256 + threadIdx.x;  // 16384 elems
  float v = proj[i];
  projH[i] = bhi(v);
  projL[i] = bhi(v - hif(v));
  if (i < BH) stabk[i] = NEGINF;
}

// ---------------- vsum: Vs[bh][e] += sum_n mask*V (1024 blocks) ------------
__global__ __launch_bounds__(256) void vsum_kernel(
    const float* __restrict__ V, const float* __restrict__ mask,
    float* __restrict__ Vs) {
  const int bh = blockIdx.y, b = bh >> 3, t = threadIdx.x;
  const int e = t & 63, g = t >> 6;
  const int n0 = blockIdx.x * 128;
  float s = 0.f;
  for (int n = n0 + g; n < n0 + 128; n += 4)
    s += V[((size_t)bh * NN + n) * DD + e] * mask[b * NN + n];
  __shared__ float red[256];
  red[t] = s;
  __syncthreads();
  if (t < 64)
    atomicAdd(&Vs[bh * DD + t], (red[t] + red[t + 64]) + (red[t + 128] + red[t + 192]));
}

// ---------------- kside: MFMA phi_k pass -----------------------------------
// grid (32, 32), 256 thr. Block: 128 K-rows, 4 chunks of 32.
__global__ __launch_bounds__(256) void kside_kernel(
    const float* __restrict__ K, const float* __restrict__ V,
    const float* __restrict__ mask,
    const unsigned short* __restrict__ projH, const unsigned short* __restrict__ projL,
    float* __restrict__ stabk, float* __restrict__ ksE,
    float* __restrict__ ctxE) {
  const int bh = blockIdx.y, b = bh >> 3;
  const int t = threadIdx.x;
  const int w = t >> 6, l = t & 63, c = l & 15, sq = l >> 4;
  const int m0 = w * 64;

  __shared__ __align__(16) unsigned short sK[2][32 * 72];   // [plane][n][d] pad 72
  __shared__ __align__(16) unsigned short sVt[2][64 * 40];  // [plane][e][n] pad 40
  __shared__ float sDiag[32];
  __shared__ float sRed[4];
  __shared__ __align__(16) unsigned short sPhi[4][2][512];  // [w][plane][swizzled]

  // persistent B-frags of P^T from pre-split planes
  Frag Bp[4][2][2];
#pragma unroll
  for (int tt = 0; tt < 4; ++tt)
#pragma unroll
    for (int s = 0; s < 2; ++s) {
      const size_t o = (size_t)(m0 + tt * 16 + c) * DD + s * 32 + sq * 8;
      Bp[tt][s][0].s8 = *(const short8*)&projH[o];
      Bp[tt][s][1].s8 = *(const short8*)&projL[o];
    }

  floatx4 ctxacc[4][4];
#pragma unroll
  for (int i = 0; i < 4; ++i)
#pragma unroll
    for (int j = 0; j < 4; ++j) ctxacc[i][j] = (floatx4){0.f, 0.f, 0.f, 0.f};
  float ksac[4] = {0.f, 0.f, 0.f, 0.f};
  float mxloc = NEGINF;

  const int r0 = blockIdx.x * 128;

  for (int ch = 0; ch < 4; ++ch) {
    const int rb = r0 + ch * 32;
    __syncthreads();

    // ---- stage K (scaled+masked, split) + diag: vector b64 writes ----
#pragma unroll
    for (int rep = 0; rep < 2; ++rep) {
      const int f = t + rep * 256;
      const int n = f >> 4, dg = f & 15;
      const float mk = mask[b * NN + rb + n];
      const float msc = mk * SCALE;
      float4 kv = *(const float4*)(K + ((size_t)bh * NN + rb + n) * DD + dg * 4);
      float k0 = kv.x * msc, k1 = kv.y * msc, k2 = kv.z * msc, k3 = kv.w * msc;
      float ss = fmaf(k0, k0, fmaf(k1, k1, fmaf(k2, k2, k3 * k3)));
      ss += __shfl_xor(ss, 1); ss += __shfl_xor(ss, 2);
      ss += __shfl_xor(ss, 4); ss += __shfl_xor(ss, 8);
      if (dg == 0) sDiag[n] = 0.5f * ss;
      unsigned h0 = pk2(k0, k1), h1 = pk2(k2, k3);
      float q0 = k0 - hif(k0), q1 = k1 - hif(k1);
      float q2 = k2 - hif(k2), q3 = k3 - hif(k3);
      *(uint2*)(&sK[0][n * 72 + dg * 4]) = make_uint2(h0, h1);
      *(uint2*)(&sK[1][n * 72 + dg * 4]) = make_uint2(pk2(q0, q1), pk2(q2, q3));
    }

    // ---- stage V^T via wave shfl-transpose: 2 b64 writes/thread/rep ----
#pragma unroll
    for (int rep = 0; rep < 2; ++rep) {
      const int nb = w * 4 + rep * 16;   // wave's 4-column base (chunk-local n)
      const int n_loc = nb + sq;
      const float mk = mask[b * NN + rb + n_loc];
      float4 vv = *(const float4*)(V + ((size_t)bh * NN + rb + n_loc) * DD + c * 4);
      float va[4] = {vv.x * mk, vv.y * mk, vv.z * mk, vv.w * mk};
      float g[4];
#pragma unroll
      for (int k = 0; k < 4; ++k) {
        const int gi = (sq + k) & 3;
        float sel = va[(sq - k) & 3];
        g[gi] = __shfl(sel, gi * 16 + c);
      }
      // lane now holds column e* = c*4+sq, rows n = nb..nb+3
      const int estar = c * 4 + sq;
      unsigned h0 = pk2(g[0], g[1]), h1 = pk2(g[2], g[3]);
      float q0 = g[0] - hif(g[0]), q1 = g[1] - hif(g[1]);
      float q2 = g[2] - hif(g[2]), q3 = g[3] - hif(g[3]);
      *(uint2*)(&sVt[0][estar * 40 + nb]) = make_uint2(h0, h1);
      *(uint2*)(&sVt[1][estar * 40 + nb]) = make_uint2(pk2(q0, q1), pk2(q2, q3));
    }
    __syncthreads();

    // ---- frags ----
    Frag Ak[2][2][2];  // [ntile][kstep][plane]
#pragma unroll
    for (int i = 0; i < 2; ++i)
#pragma unroll
      for (int s = 0; s < 2; ++s) {
        Ak[i][s][0].s8 = *(const short8*)&sK[0][(i * 16 + c) * 72 + s * 32 + sq * 8];
        Ak[i][s][1].s8 = *(const short8*)&sK[1][(i * 16 + c) * 72 + s * 32 + sq * 8];
      }
    Frag Bv[4][2];
#pragma unroll
    for (int E = 0; E < 4; ++E) {
      Bv[E][0].s8 = *(const short8*)&sVt[0][(E * 16 + c) * 40 + sq * 8];
      Bv[E][1].s8 = *(const short8*)&sVt[1][(E * 16 + c) * 40 + sq * 8];
    }

#pragma unroll
    for (int tt = 0; tt < 4; ++tt) {
      // ---- S1: xp for both n-tiles ----
      floatx4 xacc[2];
#pragma unroll
      for (int i = 0; i < 2; ++i) {
        floatx4 a = (floatx4){0.f, 0.f, 0.f, 0.f};
#pragma unroll
        for (int s = 0; s < 2; ++s) {
          a = __builtin_amdgcn_mfma_f32_16x16x32_bf16(Ak[i][s][0].s8, Bp[tt][s][0].s8, a, 0, 0, 0);
          a = __builtin_amdgcn_mfma_f32_16x16x32_bf16(Ak[i][s][0].s8, Bp[tt][s][1].s8, a, 0, 0, 0);
          a = __builtin_amdgcn_mfma_f32_16x16x32_bf16(Ak[i][s][1].s8, Bp[tt][s][0].s8, a, 0, 0, 0);
        }
        xacc[i] = a;
      }
      // ---- S2: exp frame-0, max, ksum, phi scatter (wave-local, swizzled) ----
      const int qp_c = sq >> 1, half = (sq & 1) * 4;
#pragma unroll
      for (int i = 0; i < 2; ++i) {
        float p[4];
#pragma unroll
        for (int jj = 0; jj < 4; ++jj) {
          float xp = xacc[i][jj];
          mxloc = fmaxf(mxloc, xp);
          p[jj] = __expf(xp - sDiag[i * 16 + sq * 4 + jj]);
          ksac[tt] += p[jj];
        }
        unsigned h0 = pk2(p[0], p[1]), h1 = pk2(p[2], p[3]);
        float q0 = p[0] - hif(p[0]), q1 = p[1] - hif(p[1]);
        float q2 = p[2] - hif(p[2]), q3 = p[3] - hif(p[3]);
        const int tl = (i * 2 + qp_c) * 16 + c;
        const int idx = ph16(tl) * 8 + half;
        *(uint2*)&sPhi[w][0][idx] = make_uint2(h0, h1);
        *(uint2*)&sPhi[w][1][idx] = make_uint2(pk2(q0, q1), pk2(q2, q3));
      }
      // ---- S3: ctx += phi^T @ Vm (DS in-order per wave: no barrier) ----
      Frag Ap[2];
      Ap[0].s8 = *(const short8*)&sPhi[w][0][ph16(l) * 8];
      Ap[1].s8 = *(const short8*)&sPhi[w][1][ph16(l) * 8];
#pragma unroll
      for (int E = 0; E < 4; ++E) {
        ctxacc[tt][E] = __builtin_amdgcn_mfma_f32_16x16x32_bf16(Ap[0].s8, Bv[E][0].s8, ctxacc[tt][E], 0, 0, 0);
        ctxacc[tt][E] = __builtin_amdgcn_mfma_f32_16x16x32_bf16(Ap[0].s8, Bv[E][1].s8, ctxacc[tt][E], 0, 0, 0);
        ctxacc[tt][E] = __builtin_amdgcn_mfma_f32_16x16x32_bf16(Ap[1].s8, Bv[E][0].s8, ctxacc[tt][E], 0, 0, 0);
      }
    }
  }

  // ---- epilogue ----
#pragma unroll
  for (int tt = 0; tt < 4; ++tt) {
    float v = ksac[tt];
    v += __shfl_xor(v, 16);
    v += __shfl_xor(v, 32);
    if (sq == 0) atomicAdd(&ksE[bh * MM + m0 + tt * 16 + c], v);
  }
#pragma unroll
  for (int off = 1; off <= 32; off <<= 1) mxloc = fmaxf(mxloc, __shfl_xor(mxloc, off));
  if (l == 0) sRed[w] = mxloc;
  __syncthreads();
  if (t == 0)
    atomicMaxF(&stabk[bh], fmaxf(fmaxf(sRed[0], sRed[1]), fmaxf(sRed[2], sRed[3])));

  float* cg = ctxE + (size_t)bh * MM * DD;
#pragma unroll
  for (int tt = 0; tt < 4; ++tt)
#pragma unroll
    for (int E = 0; E < 4; ++E) {
#pragma unroll
      for (int r = 0; r < 4; ++r) {
        const int m = m0 + tt * 16 + sq * 4 + r;
        const int e = E * 16 + c;
        atomicAdd(&cg[m * DD + e], ctxacc[tt][E][r]);
      }
    }
}

// ---------------- ksfin: finalize ksum + kssum -----------------------------
__global__ __launch_bounds__(256) void ksfin_kernel(
    const float* __restrict__ stabk, const float* __restrict__ ksE,
    float* __restrict__ ksum, float* __restrict__ kssum) {
  const int bh = blockIdx.x, t = threadIdx.x;
  const float es = __expf(-stabk[bh]);
  __shared__ float red[256];
  const float kv = RATIO * (es * ksE[bh * MM + t] + (float)NN * EPSI);
  ksum[bh * MM + t] = kv;
  red[t] = kv;
  __syncthreads();
  for (int off = 128; off >= 1; off >>= 1) {
    if (t < off) red[t] += red[t + off];
    __syncthreads();
  }
  if (t == 0) kssum[bh] = red[0];
}

// ---------------- fixup: ctx scale+eps -> ctxT split planes (tiled) --------
// grid (4 mchunks, 32 bh). Coalesced reads of ctxE[m][e], LDS 65-pad
// transpose, coalesced u16 writes of ctxTH/L[e][m]. ctxsum via atomics.
__global__ __launch_bounds__(256) void fixup_kernel(
    const float* __restrict__ stabk, const float* __restrict__ Vs,
    const float* __restrict__ ctxE, float* __restrict__ ctxsum,
    unsigned short* __restrict__ ctxTH, unsigned short* __restrict__ ctxTL) {
  const int bh = blockIdx.y, mc = blockIdx.x, t = threadIdx.x;
  const float es = __expf(-stabk[bh]);
  const int e = t & 63, g = t >> 6;
  const float vse = EPSI * Vs[bh * DD + e];

  __shared__ float tile[64 * 65];
  __shared__ float cred[256];

  float csum = 0.f;
#pragma unroll
  for (int r = 0; r < 16; ++r) {
    const int ml = r * 4 + g;
    float x = ctxE[(size_t)(bh * MM + mc * 64 + ml) * DD + e];
    float v = RATIO * (es * x + vse);
    csum += v;
    tile[e * 65 + ml] = v;
  }
  cred[t] = csum;
  __syncthreads();
  if (t < 64)
    atomicAdd(&ctxsum[bh * DD + t],
              (cred[t] + cred[t + 64]) + (cred[t + 128] + cred[t + 192]));
#pragma unroll
  for (int r = 0; r < 16; ++r) {
    const int el = r * 4 + g, ml = t & 63;
    float v = tile[el * 65 + ml];
    const size_t o = ((size_t)(bh * DD + el)) * MM + mc * 64 + ml;
    ctxTH[o] = bhi(v);
    ctxTL[o] = bhi(v - hif(v));
  }
}

// ---------------- out: MFMA Q side (round-4 verbatim) ----------------------
__global__ __launch_bounds__(256, 2) void out_kernel(
    const float* __restrict__ Q,
    const unsigned short* __restrict__ projH, const unsigned short* __restrict__ projL,
    const float* __restrict__ ksum,
    const unsigned short* __restrict__ ctxTH, const unsigned short* __restrict__ ctxTL,
    const float* __restrict__ kssum, const float* __restrict__ ctxsum,
    float* __restrict__ out) {
  const int bh = blockIdx.y;
  const int r0 = blockIdx.x * 64;
  const int t = threadIdx.x, w = t >> 6, l = t & 63, c = l & 15, sq = l >> 4;

  __shared__ __align__(16) unsigned short sQ[2][64 * 80];
  __shared__ __align__(16) unsigned short sP[2][64 * 80];
  __shared__ __align__(16) unsigned short sC[2][64 * 80];
  __shared__ float sKs[256];
  __shared__ float sDiag[64];
  __shared__ __align__(16) unsigned short sPhi[4][2][2][512];

  {
    const int row = t >> 2, q4 = t & 3;
    const float* qp = Q + ((size_t)bh * NN + r0 + row) * DD + q4 * 16;
    float4 t0 = *(const float4*)(qp + 0), t1 = *(const float4*)(qp + 4),
           t2 = *(const float4*)(qp + 8), t3 = *(const float4*)(qp + 12);
    float v[16] = {t0.x, t0.y, t0.z, t0.w, t1.x, t1.y, t1.z, t1.w,
                   t2.x, t2.y, t2.z, t2.w, t3.x, t3.y, t3.z, t3.w};
    float ss = 0.f;
#pragma unroll
    for (int j = 0; j < 16; ++j) { v[j] *= SCALE; ss = fmaf(v[j], v[j], ss); }
    ss += __shfl_xor(ss, 1);
    ss += __shfl_xor(ss, 2);
    if (q4 == 0) sDiag[row] = 0.5f * ss;
    unsigned short* dh = &sQ[0][row * 80 + q4 * 16];
    unsigned short* dl = &sQ[1][row * 80 + q4 * 16];
#pragma unroll
    for (int j = 0; j < 8; ++j) {
      *(unsigned*)&dh[2 * j] = pk2(v[2 * j], v[2 * j + 1]);
      float l0 = v[2 * j] - hif(v[2 * j]), l1 = v[2 * j + 1] - hif(v[2 * j + 1]);
      *(unsigned*)&dl[2 * j] = pk2(l0, l1);
    }
  }
  sKs[t] = ksum[bh * MM + t];
  __syncthreads();

  Frag Bq[2][2];
#pragma unroll
  for (int s = 0; s < 2; ++s)
#pragma unroll
    for (int p = 0; p < 2; ++p)
      Bq[s][p].s8 = *(const short8*)&sQ[p][(w * 16 + c) * 80 + s * 32 + sq * 8];

  const float diagc = sDiag[w * 16 + c];
  floatx4 oacc[4];
#pragma unroll
  for (int E = 0; E < 4; ++E) oacc[E] = (floatx4){0.f, 0.f, 0.f, 0.f};
  float mxacc = NEGINF, dsacc = 0.f;

  for (int mc = 0; mc < 4; ++mc) {
    __syncthreads();
    {
      const int row = t >> 2, q4 = t & 3;
      const size_t gp = (size_t)(mc * 64 + row) * DD + q4 * 16;
      const uint4* ph = (const uint4*)&projH[gp];
      const uint4* pl = (const uint4*)&projL[gp];
      *(uint4*)&sP[0][row * 80 + q4 * 16] = ph[0];
      *(uint4*)&sP[0][row * 80 + q4 * 16 + 8] = ph[1];
      *(uint4*)&sP[1][row * 80 + q4 * 16] = pl[0];
      *(uint4*)&sP[1][row * 80 + q4 * 16 + 8] = pl[1];
      const size_t gc = ((size_t)bh * DD + row) * MM + mc * 64 + q4 * 16;
      const uint4* chh = (const uint4*)&ctxTH[gc];
      const uint4* cll = (const uint4*)&ctxTL[gc];
      *(uint4*)&sC[0][row * 80 + q4 * 16] = chh[0];
      *(uint4*)&sC[0][row * 80 + q4 * 16 + 8] = chh[1];
      *(uint4*)&sC[1][row * 80 + q4 * 16] = cll[0];
      *(uint4*)&sC[1][row * 80 + q4 * 16 + 8] = cll[1];
    }
    __syncthreads();

#pragma unroll
    for (int tt = 0; tt < 4; ++tt) {
      Frag Af[2][2];
#pragma unroll
      for (int s = 0; s < 2; ++s)
#pragma unroll
        for (int p = 0; p < 2; ++p)
          Af[s][p].s8 = *(const short8*)&sP[p][(tt * 16 + c) * 80 + s * 32 + sq * 8];
      floatx4 x = (floatx4){0.f, 0.f, 0.f, 0.f};
#pragma unroll
      for (int s = 0; s < 2; ++s) {
        x = __builtin_amdgcn_mfma_f32_16x16x32_bf16(Af[s][0].s8, Bq[s][0].s8, x, 0, 0, 0);
        x = __builtin_amdgcn_mfma_f32_16x16x32_bf16(Af[s][0].s8, Bq[s][1].s8, x, 0, 0, 0);
        x = __builtin_amdgcn_mfma_f32_16x16x32_bf16(Af[s][1].s8, Bq[s][0].s8, x, 0, 0, 0);
      }
      float p4[4];
#pragma unroll
      for (int jj = 0; jj < 4; ++jj) {
        const float xp = x[jj];
        mxacc = fmaxf(mxacc, xp);
        p4[jj] = __expf(xp - diagc);
        dsacc = fmaf(p4[jj], sKs[mc * 64 + tt * 16 + sq * 4 + jj], dsacc);
      }
      const int kstep = tt >> 1;
      const int tl = ((tt & 1) * 2 + (sq >> 1)) * 16 + c;
      const int off = (sq & 1) * 4;
      float l0 = p4[0] - hif(p4[0]), l1 = p4[1] - hif(p4[1]);
      float l2 = p4[2] - hif(p4[2]), l3 = p4[3] - hif(p4[3]);
      *(uint2*)&sPhi[w][0][kstep][tl * 8 + off] = make_uint2(pk2(p4[0], p4[1]), pk2(p4[2], p4[3]));
      *(uint2*)&sPhi[w][1][kstep][tl * 8 + off] = make_uint2(pk2(l0, l1), pk2(l2, l3));
    }

#pragma unroll
    for (int ks = 0; ks < 2; ++ks) {
      Frag Aph[2];
      Aph[0].s8 = *(const short8*)&sPhi[w][0][ks][l * 8];
      Aph[1].s8 = *(const short8*)&sPhi[w][1][ks][l * 8];
#pragma unroll
      for (int E = 0; E < 4; ++E) {
        Frag Bc0, Bc1;
        Bc0.s8 = *(const short8*)&sC[0][(E * 16 + c) * 80 + ks * 32 + sq * 8];
        Bc1.s8 = *(const short8*)&sC[1][(E * 16 + c) * 80 + ks * 32 + sq * 8];
        oacc[E] = __builtin_amdgcn_mfma_f32_16x16x32_bf16(Aph[0].s8, Bc0.s8, oacc[E], 0, 0, 0);
        oacc[E] = __builtin_amdgcn_mfma_f32_16x16x32_bf16(Aph[0].s8, Bc1.s8, oacc[E], 0, 0, 0);
        oacc[E] = __builtin_amdgcn_mfma_f32_16x16x32_bf16(Aph[1].s8, Bc0.s8, oacc[E], 0, 0, 0);
      }
    }
  }

  mxacc = fmaxf(mxacc, __shfl_xor(mxacc, 16));
  mxacc = fmaxf(mxacc, __shfl_xor(mxacc, 32));
  dsacc += __shfl_xor(dsacc, 16);
  dsacc += __shfl_xor(dsacc, 32);

  const float kss = kssum[bh];
  float fac[4], oinv[4];
#pragma unroll
  for (int jj = 0; jj < 4; ++jj) {
    const int src = sq * 4 + jj;
    const float s_row = __shfl(mxacc, src);
    const float d_row = __shfl(dsacc, src);
    const float f = __expf(s_row) * EPSI;
    fac[jj] = f;
    oinv[jj] = 1.f / (d_row + f * kss);
  }

  const float* csb = ctxsum + bh * DD;
#pragma unroll
  for (int E = 0; E < 4; ++E) {
    const float cse = csb[E * 16 + c];
#pragma unroll
    for (int jj = 0; jj < 4; ++jj) {
      const int row = r0 + w * 16 + sq * 4 + jj;
      out[((size_t)bh * NN + row) * DD + E * 16 + c] =
          (oacc[E][jj] + fac[jj] * cse) * oinv[jj];
    }
  }
}

extern "C" void kernel_launch(void* const* d_in, const int* in_sizes, int n_in,
                              void* d_out, int out_size, void* d_ws, size_t ws_size,
                              hipStream_t stream) {
  const float* Q    = (const float*)d_in[0];
  const float* K    = (const float*)d_in[1];
  const float* V    = (const float*)d_in[2];
  const float* mask = (const float*)d_in[3];
  const float* proj = (const float*)d_in[4];
  float* out = (float*)d_out;

  float* wsf = (float*)d_ws;
  float* stabk  = wsf;                          // 32
  float* ksum   = wsf + 32;                     // 8192
  float* kssum  = wsf + 8224;                   // 32
  unsigned short* projH = (unsigned short*)(wsf + 8256);    // 16384 shorts
  unsigned short* projL = (unsigned short*)(wsf + 16448);   // 16384 shorts
  unsigned short* ctxTH = (unsigned short*)(wsf + 24640);   // 524288 shorts
  unsigned short* ctxTL = (unsigned short*)(wsf + 286784);  // 524288 shorts
  // zero region (atomically accumulated):
  float* Vs     = wsf + 548928;                 // 2048
  float* ctxsum = wsf + 550976;                 // 2048
  float* ksE    = wsf + 553024;                 // 8192
  float* ctxE   = wsf + 561216;                 // 524288; end 1085504 (~4.3MB)

  hipMemsetAsync(wsf + 548928, 0, (2048 + 2048 + 8192 + 524288) * sizeof(float), stream);

  prep_kernel<<<64, 256, 0, stream>>>(proj, projH, projL, stabk);
  vsum_kernel<<<dim3(32, BH), 256, 0, stream>>>(V, mask, Vs);
  kside_kernel<<<dim3(32, BH), 256, 0, stream>>>(K, V, mask, projH, projL, stabk, ksE, ctxE);
  ksfin_kernel<<<BH, 256, 0, stream>>>(stabk, ksE, ksum, kssum);
  fixup_kernel<<<dim3(4, BH), 256, 0, stream>>>(stabk, Vs, ctxE, ctxsum, ctxTH, ctxTL);
  out_kernel<<<dim3(64, BH), 256, 0, stream>>>(Q, projH, projL, ksum, ctxTH, ctxTL, kssum, ctxsum, out);
}

// Round 6
// 255.969 us; speedup vs baseline: 1.1706x; 1.1706x over previous
//
#include <hip/hip_runtime.h>
#include <hip/hip_bf16.h>

// Performer (FAVOR+) attention. B=4 H=8 N=4096 D=64 M=256.
// Round-6:
//  - kside: back to 16 chunks/head (round-5's 32 doubled atomic traffic ->
//    regression). ctx partials now PLAIN-STORED to private slices (no RMW),
//    reduced in fixup; runtime ws_size check falls back to atomic path.
//  - vsum folded into kside (it already holds masked V in regs).
//  - ksfin folded into fixup (mc==0 blocks).
//  - launches 7 -> 4 (prep, kside, fixup, out); memset only in fallback.

typedef __attribute__((ext_vector_type(8))) short short8;
typedef __attribute__((ext_vector_type(4))) float floatx4;

constexpr int BB = 4, HH = 8, NN = 4096, DD = 64, MM = 256, BH = 32;
constexpr int NCH = 16;  // n-chunks per head (kside grid.x)
constexpr float SCALE = 0.3535533905932738f;  // 64^-0.25
constexpr float RATIO = 0.0625f;              // 256^-0.5
constexpr float EPSI  = 1e-4f;
constexpr float NEGINF = -3.4e38f;

__device__ inline unsigned pk2(float a, float b) {
  unsigned ua = __float_as_uint(a) + 0x8000u;
  unsigned ub = __float_as_uint(b) + 0x8000u;
  return (ua >> 16) | (ub & 0xffff0000u);
}
__device__ inline float hif(float x) {
  return __uint_as_float((__float_as_uint(x) + 0x8000u) & 0xffff0000u);
}
__device__ inline unsigned short bhi(float x) {
  return (unsigned short)((__float_as_uint(x) + 0x8000u) >> 16);
}
__device__ inline int ph16(int i) { return (i & 56) | ((i + (i >> 3)) & 7); }

union Frag { short8 s8; unsigned u[4]; };

__device__ inline void atomicMaxF(float* a, float v) {
  unsigned* ai = (unsigned*)a;
  unsigned old = __atomic_load_n(ai, __ATOMIC_RELAXED);
  while (__uint_as_float(old) < v) {
    unsigned assumed = old;
    old = atomicCAS(ai, assumed, __float_as_uint(v));
    if (old == assumed) break;
  }
}

// ---------------- prep: split proj; init stabk; zero small accumulators ----
__global__ __launch_bounds__(256) void prep_kernel(
    const float* __restrict__ proj, unsigned short* __restrict__ projH,
    unsigned short* __restrict__ projL, float* __restrict__ stabk,
    float* __restrict__ Vs, float* __restrict__ ctxsum,
    float* __restrict__ ksE) {
  const int i = blockIdx.x * 256 + threadIdx.x;  // 16384 elems
  float v = proj[i];
  projH[i] = bhi(v);
  projL[i] = bhi(v - hif(v));
  if (i < BH) stabk[i] = NEGINF;
  if (i < 2048) { Vs[i] = 0.f; ctxsum[i] = 0.f; }
  if (i < 8192) ksE[i] = 0.f;
}

// ---------------- kside: MFMA phi_k pass -----------------------------------
// grid (NCH, 32), 256 thr. Block: 256 K-rows, 8 chunks of 32.
// PARTIAL: plain-store ctx partial to private slice; else atomicAdd to ctxE.
template <bool PARTIAL>
__global__ __launch_bounds__(256) void kside_kernel(
    const float* __restrict__ K, const float* __restrict__ V,
    const float* __restrict__ mask,
    const unsigned short* __restrict__ projH, const unsigned short* __restrict__ projL,
    float* __restrict__ stabk, float* __restrict__ ksE,
    float* __restrict__ ctxOut, float* __restrict__ Vs) {
  const int bh = blockIdx.y, b = bh >> 3;
  const int t = threadIdx.x;
  const int w = t >> 6, l = t & 63, c = l & 15, sq = l >> 4;
  const int m0 = w * 64;

  __shared__ __align__(16) unsigned short sK[2][32 * 72];   // [plane][n][d] pad 72
  __shared__ __align__(16) unsigned short sVt[2][64 * 40];  // [plane][e][n] pad 40
  __shared__ float sDiag[32];
  __shared__ float sRed[4];
  __shared__ float sVsum[4][64];
  __shared__ __align__(16) unsigned short sPhi[4][2][512];  // [w][plane][swizzled]

  // persistent B-frags of P^T from pre-split planes
  Frag Bp[4][2][2];
#pragma unroll
  for (int tt = 0; tt < 4; ++tt)
#pragma unroll
    for (int s = 0; s < 2; ++s) {
      const size_t o = (size_t)(m0 + tt * 16 + c) * DD + s * 32 + sq * 8;
      Bp[tt][s][0].s8 = *(const short8*)&projH[o];
      Bp[tt][s][1].s8 = *(const short8*)&projL[o];
    }

  floatx4 ctxacc[4][4];
#pragma unroll
  for (int i = 0; i < 4; ++i)
#pragma unroll
    for (int j = 0; j < 4; ++j) ctxacc[i][j] = (floatx4){0.f, 0.f, 0.f, 0.f};
  float ksac[4] = {0.f, 0.f, 0.f, 0.f};
  float mxloc = NEGINF;
  float vsacc = 0.f;  // masked V column-sum partial (column estar = c*4+sq)

  const int r0 = blockIdx.x * 256;

  for (int ch = 0; ch < 8; ++ch) {
    const int rb = r0 + ch * 32;
    __syncthreads();

    // ---- stage K (scaled+masked, split) + diag ----
#pragma unroll
    for (int rep = 0; rep < 2; ++rep) {
      const int f = t + rep * 256;
      const int n = f >> 4, dg = f & 15;
      const float mk = mask[b * NN + rb + n];
      const float msc = mk * SCALE;
      float4 kv = *(const float4*)(K + ((size_t)bh * NN + rb + n) * DD + dg * 4);
      float k0 = kv.x * msc, k1 = kv.y * msc, k2 = kv.z * msc, k3 = kv.w * msc;
      float ss = fmaf(k0, k0, fmaf(k1, k1, fmaf(k2, k2, k3 * k3)));
      ss += __shfl_xor(ss, 1); ss += __shfl_xor(ss, 2);
      ss += __shfl_xor(ss, 4); ss += __shfl_xor(ss, 8);
      if (dg == 0) sDiag[n] = 0.5f * ss;
      unsigned h0 = pk2(k0, k1), h1 = pk2(k2, k3);
      float q0 = k0 - hif(k0), q1 = k1 - hif(k1);
      float q2 = k2 - hif(k2), q3 = k3 - hif(k3);
      *(uint2*)(&sK[0][n * 72 + dg * 4]) = make_uint2(h0, h1);
      *(uint2*)(&sK[1][n * 72 + dg * 4]) = make_uint2(pk2(q0, q1), pk2(q2, q3));
    }

    // ---- stage V^T via wave shfl-transpose; accumulate Vs partial ----
#pragma unroll
    for (int rep = 0; rep < 2; ++rep) {
      const int nb = w * 4 + rep * 16;
      const int n_loc = nb + sq;
      const float mk = mask[b * NN + rb + n_loc];
      float4 vv = *(const float4*)(V + ((size_t)bh * NN + rb + n_loc) * DD + c * 4);
      float va[4] = {vv.x * mk, vv.y * mk, vv.z * mk, vv.w * mk};
      float g[4];
#pragma unroll
      for (int k = 0; k < 4; ++k) {
        const int gi = (sq + k) & 3;
        float sel = va[(sq - k) & 3];
        g[gi] = __shfl(sel, gi * 16 + c);
      }
      const int estar = c * 4 + sq;  // lane's column, rows nb..nb+3
      vsacc += ((g[0] + g[1]) + (g[2] + g[3]));
      unsigned h0 = pk2(g[0], g[1]), h1 = pk2(g[2], g[3]);
      float q0 = g[0] - hif(g[0]), q1 = g[1] - hif(g[1]);
      float q2 = g[2] - hif(g[2]), q3 = g[3] - hif(g[3]);
      *(uint2*)(&sVt[0][estar * 40 + nb]) = make_uint2(h0, h1);
      *(uint2*)(&sVt[1][estar * 40 + nb]) = make_uint2(pk2(q0, q1), pk2(q2, q3));
    }
    __syncthreads();

    // ---- frags ----
    Frag Ak[2][2][2];
#pragma unroll
    for (int i = 0; i < 2; ++i)
#pragma unroll
      for (int s = 0; s < 2; ++s) {
        Ak[i][s][0].s8 = *(const short8*)&sK[0][(i * 16 + c) * 72 + s * 32 + sq * 8];
        Ak[i][s][1].s8 = *(const short8*)&sK[1][(i * 16 + c) * 72 + s * 32 + sq * 8];
      }
    Frag Bv[4][2];
#pragma unroll
    for (int E = 0; E < 4; ++E) {
      Bv[E][0].s8 = *(const short8*)&sVt[0][(E * 16 + c) * 40 + sq * 8];
      Bv[E][1].s8 = *(const short8*)&sVt[1][(E * 16 + c) * 40 + sq * 8];
    }

#pragma unroll
    for (int tt = 0; tt < 4; ++tt) {
      // S1: xp for both n-tiles
      floatx4 xacc[2];
#pragma unroll
      for (int i = 0; i < 2; ++i) {
        floatx4 a = (floatx4){0.f, 0.f, 0.f, 0.f};
#pragma unroll
        for (int s = 0; s < 2; ++s) {
          a = __builtin_amdgcn_mfma_f32_16x16x32_bf16(Ak[i][s][0].s8, Bp[tt][s][0].s8, a, 0, 0, 0);
          a = __builtin_amdgcn_mfma_f32_16x16x32_bf16(Ak[i][s][0].s8, Bp[tt][s][1].s8, a, 0, 0, 0);
          a = __builtin_amdgcn_mfma_f32_16x16x32_bf16(Ak[i][s][1].s8, Bp[tt][s][0].s8, a, 0, 0, 0);
        }
        xacc[i] = a;
      }
      // S2: exp frame-0, max, ksum, phi scatter (wave-local, swizzled)
      const int qp_c = sq >> 1, half = (sq & 1) * 4;
#pragma unroll
      for (int i = 0; i < 2; ++i) {
        float p[4];
#pragma unroll
        for (int jj = 0; jj < 4; ++jj) {
          float xp = xacc[i][jj];
          mxloc = fmaxf(mxloc, xp);
          p[jj] = __expf(xp - sDiag[i * 16 + sq * 4 + jj]);
          ksac[tt] += p[jj];
        }
        unsigned h0 = pk2(p[0], p[1]), h1 = pk2(p[2], p[3]);
        float q0 = p[0] - hif(p[0]), q1 = p[1] - hif(p[1]);
        float q2 = p[2] - hif(p[2]), q3 = p[3] - hif(p[3]);
        const int tl = (i * 2 + qp_c) * 16 + c;
        const int idx = ph16(tl) * 8 + half;
        *(uint2*)&sPhi[w][0][idx] = make_uint2(h0, h1);
        *(uint2*)&sPhi[w][1][idx] = make_uint2(pk2(q0, q1), pk2(q2, q3));
      }
      // S3: ctx += phi^T @ Vm (wave-local DS ordering: no barrier needed)
      Frag Ap[2];
      Ap[0].s8 = *(const short8*)&sPhi[w][0][ph16(l) * 8];
      Ap[1].s8 = *(const short8*)&sPhi[w][1][ph16(l) * 8];
#pragma unroll
      for (int E = 0; E < 4; ++E) {
        ctxacc[tt][E] = __builtin_amdgcn_mfma_f32_16x16x32_bf16(Ap[0].s8, Bv[E][0].s8, ctxacc[tt][E], 0, 0, 0);
        ctxacc[tt][E] = __builtin_amdgcn_mfma_f32_16x16x32_bf16(Ap[0].s8, Bv[E][1].s8, ctxacc[tt][E], 0, 0, 0);
        ctxacc[tt][E] = __builtin_amdgcn_mfma_f32_16x16x32_bf16(Ap[1].s8, Bv[E][0].s8, ctxacc[tt][E], 0, 0, 0);
      }
    }
  }

  // ---- epilogue: ksum partials, block max, Vs partial, ctx out ----
#pragma unroll
  for (int tt = 0; tt < 4; ++tt) {
    float v = ksac[tt];
    v += __shfl_xor(v, 16);
    v += __shfl_xor(v, 32);
    if (sq == 0) atomicAdd(&ksE[bh * MM + m0 + tt * 16 + c], v);
  }
#pragma unroll
  for (int off = 1; off <= 32; off <<= 1) mxloc = fmaxf(mxloc, __shfl_xor(mxloc, off));
  if (l == 0) sRed[w] = mxloc;
  sVsum[w][c * 4 + sq] = vsacc;
  __syncthreads();
  if (t == 0)
    atomicMaxF(&stabk[bh], fmaxf(fmaxf(sRed[0], sRed[1]), fmaxf(sRed[2], sRed[3])));
  if (t < 64)
    atomicAdd(&Vs[bh * DD + t],
              (sVsum[0][t] + sVsum[1][t]) + (sVsum[2][t] + sVsum[3][t]));

  if (PARTIAL) {
    float* cg = ctxOut + ((size_t)(bh * NCH + blockIdx.x) * MM) * DD;
#pragma unroll
    for (int tt = 0; tt < 4; ++tt)
#pragma unroll
      for (int E = 0; E < 4; ++E)
#pragma unroll
        for (int r = 0; r < 4; ++r)
          cg[(m0 + tt * 16 + sq * 4 + r) * DD + E * 16 + c] = ctxacc[tt][E][r];
  } else {
    float* cg = ctxOut + (size_t)bh * MM * DD;
#pragma unroll
    for (int tt = 0; tt < 4; ++tt)
#pragma unroll
      for (int E = 0; E < 4; ++E)
#pragma unroll
        for (int r = 0; r < 4; ++r)
          atomicAdd(&cg[(m0 + tt * 16 + sq * 4 + r) * DD + E * 16 + c],
                    ctxacc[tt][E][r]);
  }
}

// ---------------- fixup: reduce partials, scale+eps, emit ctxT; ksfin ------
// grid (8 mchunks of 32, 32 bh), 256 thr.
template <int NPARTS>
__global__ __launch_bounds__(256) void fixup_kernel(
    const float* __restrict__ stabk, const float* __restrict__ Vs,
    const float* __restrict__ ksE, const float* __restrict__ ctxParts,
    float* __restrict__ ksum, float* __restrict__ kssum,
    float* __restrict__ ctxsum, unsigned short* __restrict__ ctxTH,
    unsigned short* __restrict__ ctxTL) {
  const int bh = blockIdx.y, mc = blockIdx.x, t = threadIdx.x;
  const float es = __expf(-stabk[bh]);
  const int e = t & 63, g = t >> 6;
  const float vse = EPSI * Vs[bh * DD + e];

  __shared__ float tile[64 * 33];  // [e][ml] ml<32
  __shared__ float cred[256];

  float csum = 0.f;
#pragma unroll
  for (int r = 0; r < 8; ++r) {
    const int ml = r * 4 + g;        // m-local in 32-chunk
    const int m = mc * 32 + ml;
    float x = 0.f;
#pragma unroll
    for (int p = 0; p < NPARTS; ++p)
      x += ctxParts[(((size_t)bh * NPARTS + p) * MM + m) * DD + e];
    float v = RATIO * (es * x + vse);
    csum += v;
    tile[e * 33 + ml] = v;
  }
  cred[t] = csum;
  __syncthreads();
  if (t < 64)
    atomicAdd(&ctxsum[bh * DD + t],
              (cred[t] + cred[t + 64]) + (cred[t + 128] + cred[t + 192]));

  // coalesced transposed write-out
  {
    const int ml5 = t & 31, elg = t >> 5;
#pragma unroll
    for (int r = 0; r < 8; ++r) {
      const int el = r * 8 + elg;
      float v = tile[el * 33 + ml5];
      const size_t o = ((size_t)(bh * DD + el)) * MM + mc * 32 + ml5;
      ctxTH[o] = bhi(v);
      ctxTL[o] = bhi(v - hif(v));
    }
  }

  // ksfin fold (one block column per head)
  if (mc == 0) {
    __syncthreads();
    const float kv = RATIO * (es * ksE[bh * MM + t] + (float)NN * EPSI);
    ksum[bh * MM + t] = kv;
    cred[t] = kv;
    __syncthreads();
    for (int off = 128; off >= 1; off >>= 1) {
      if (t < off) cred[t] += cred[t + off];
      __syncthreads();
    }
    if (t == 0) kssum[bh] = cred[0];
  }
}

// ---------------- out: MFMA Q side (round-4 verbatim, validated) -----------
__global__ __launch_bounds__(256, 2) void out_kernel(
    const float* __restrict__ Q,
    const unsigned short* __restrict__ projH, const unsigned short* __restrict__ projL,
    const float* __restrict__ ksum,
    const unsigned short* __restrict__ ctxTH, const unsigned short* __restrict__ ctxTL,
    const float* __restrict__ kssum, const float* __restrict__ ctxsum,
    float* __restrict__ out) {
  const int bh = blockIdx.y;
  const int r0 = blockIdx.x * 64;
  const int t = threadIdx.x, w = t >> 6, l = t & 63, c = l & 15, sq = l >> 4;

  __shared__ __align__(16) unsigned short sQ[2][64 * 80];
  __shared__ __align__(16) unsigned short sP[2][64 * 80];
  __shared__ __align__(16) unsigned short sC[2][64 * 80];
  __shared__ float sKs[256];
  __shared__ float sDiag[64];
  __shared__ __align__(16) unsigned short sPhi[4][2][2][512];

  {
    const int row = t >> 2, q4 = t & 3;
    const float* qp = Q + ((size_t)bh * NN + r0 + row) * DD + q4 * 16;
    float4 t0 = *(const float4*)(qp + 0), t1 = *(const float4*)(qp + 4),
           t2 = *(const float4*)(qp + 8), t3 = *(const float4*)(qp + 12);
    float v[16] = {t0.x, t0.y, t0.z, t0.w, t1.x, t1.y, t1.z, t1.w,
                   t2.x, t2.y, t2.z, t2.w, t3.x, t3.y, t3.z, t3.w};
    float ss = 0.f;
#pragma unroll
    for (int j = 0; j < 16; ++j) { v[j] *= SCALE; ss = fmaf(v[j], v[j], ss); }
    ss += __shfl_xor(ss, 1);
    ss += __shfl_xor(ss, 2);
    if (q4 == 0) sDiag[row] = 0.5f * ss;
    unsigned short* dh = &sQ[0][row * 80 + q4 * 16];
    unsigned short* dl = &sQ[1][row * 80 + q4 * 16];
#pragma unroll
    for (int j = 0; j < 8; ++j) {
      *(unsigned*)&dh[2 * j] = pk2(v[2 * j], v[2 * j + 1]);
      float l0 = v[2 * j] - hif(v[2 * j]), l1 = v[2 * j + 1] - hif(v[2 * j + 1]);
      *(unsigned*)&dl[2 * j] = pk2(l0, l1);
    }
  }
  sKs[t] = ksum[bh * MM + t];
  __syncthreads();

  Frag Bq[2][2];
#pragma unroll
  for (int s = 0; s < 2; ++s)
#pragma unroll
    for (int p = 0; p < 2; ++p)
      Bq[s][p].s8 = *(const short8*)&sQ[p][(w * 16 + c) * 80 + s * 32 + sq * 8];

  const float diagc = sDiag[w * 16 + c];
  floatx4 oacc[4];
#pragma unroll
  for (int E = 0; E < 4; ++E) oacc[E] = (floatx4){0.f, 0.f, 0.f, 0.f};
  float mxacc = NEGINF, dsacc = 0.f;

  for (int mc = 0; mc < 4; ++mc) {
    __syncthreads();
    {
      const int row = t >> 2, q4 = t & 3;
      const size_t gp = (size_t)(mc * 64 + row) * DD + q4 * 16;
      const uint4* ph = (const uint4*)&projH[gp];
      const uint4* pl = (const uint4*)&projL[gp];
      *(uint4*)&sP[0][row * 80 + q4 * 16] = ph[0];
      *(uint4*)&sP[0][row * 80 + q4 * 16 + 8] = ph[1];
      *(uint4*)&sP[1][row * 80 + q4 * 16] = pl[0];
      *(uint4*)&sP[1][row * 80 + q4 * 16 + 8] = pl[1];
      const size_t gc = ((size_t)bh * DD + row) * MM + mc * 64 + q4 * 16;
      const uint4* chh = (const uint4*)&ctxTH[gc];
      const uint4* cll = (const uint4*)&ctxTL[gc];
      *(uint4*)&sC[0][row * 80 + q4 * 16] = chh[0];
      *(uint4*)&sC[0][row * 80 + q4 * 16 + 8] = chh[1];
      *(uint4*)&sC[1][row * 80 + q4 * 16] = cll[0];
      *(uint4*)&sC[1][row * 80 + q4 * 16 + 8] = cll[1];
    }
    __syncthreads();

#pragma unroll
    for (int tt = 0; tt < 4; ++tt) {
      Frag Af[2][2];
#pragma unroll
      for (int s = 0; s < 2; ++s)
#pragma unroll
        for (int p = 0; p < 2; ++p)
          Af[s][p].s8 = *(const short8*)&sP[p][(tt * 16 + c) * 80 + s * 32 + sq * 8];
      floatx4 x = (floatx4){0.f, 0.f, 0.f, 0.f};
#pragma unroll
      for (int s = 0; s < 2; ++s) {
        x = __builtin_amdgcn_mfma_f32_16x16x32_bf16(Af[s][0].s8, Bq[s][0].s8, x, 0, 0, 0);
        x = __builtin_amdgcn_mfma_f32_16x16x32_bf16(Af[s][0].s8, Bq[s][1].s8, x, 0, 0, 0);
        x = __builtin_amdgcn_mfma_f32_16x16x32_bf16(Af[s][1].s8, Bq[s][0].s8, x, 0, 0, 0);
      }
      float p4[4];
#pragma unroll
      for (int jj = 0; jj < 4; ++jj) {
        const float xp = x[jj];
        mxacc = fmaxf(mxacc, xp);
        p4[jj] = __expf(xp - diagc);
        dsacc = fmaf(p4[jj], sKs[mc * 64 + tt * 16 + sq * 4 + jj], dsacc);
      }
      const int kstep = tt >> 1;
      const int tl = ((tt & 1) * 2 + (sq >> 1)) * 16 + c;
      const int off = (sq & 1) * 4;
      float l0 = p4[0] - hif(p4[0]), l1 = p4[1] - hif(p4[1]);
      float l2 = p4[2] - hif(p4[2]), l3 = p4[3] - hif(p4[3]);
      *(uint2*)&sPhi[w][0][kstep][tl * 8 + off] = make_uint2(pk2(p4[0], p4[1]), pk2(p4[2], p4[3]));
      *(uint2*)&sPhi[w][1][kstep][tl * 8 + off] = make_uint2(pk2(l0, l1), pk2(l2, l3));
    }

#pragma unroll
    for (int ks = 0; ks < 2; ++ks) {
      Frag Aph[2];
      Aph[0].s8 = *(const short8*)&sPhi[w][0][ks][l * 8];
      Aph[1].s8 = *(const short8*)&sPhi[w][1][ks][l * 8];
#pragma unroll
      for (int E = 0; E < 4; ++E) {
        Frag Bc0, Bc1;
        Bc0.s8 = *(const short8*)&sC[0][(E * 16 + c) * 80 + ks * 32 + sq * 8];
        Bc1.s8 = *(const short8*)&sC[1][(E * 16 + c) * 80 + ks * 32 + sq * 8];
        oacc[E] = __builtin_amdgcn_mfma_f32_16x16x32_bf16(Aph[0].s8, Bc0.s8, oacc[E], 0, 0, 0);
        oacc[E] = __builtin_amdgcn_mfma_f32_16x16x32_bf16(Aph[0].s8, Bc1.s8, oacc[E], 0, 0, 0);
        oacc[E] = __builtin_amdgcn_mfma_f32_16x16x32_bf16(Aph[1].s8, Bc0.s8, oacc[E], 0, 0, 0);
      }
    }
  }

  mxacc = fmaxf(mxacc, __shfl_xor(mxacc, 16));
  mxacc = fmaxf(mxacc, __shfl_xor(mxacc, 32));
  dsacc += __shfl_xor(dsacc, 16);
  dsacc += __shfl_xor(dsacc, 32);

  const float kss = kssum[bh];
  float fac[4], oinv[4];
#pragma unroll
  for (int jj = 0; jj < 4; ++jj) {
    const int src = sq * 4 + jj;
    const float s_row = __shfl(mxacc, src);
    const float d_row = __shfl(dsacc, src);
    const float f = __expf(s_row) * EPSI;
    fac[jj] = f;
    oinv[jj] = 1.f / (d_row + f * kss);
  }

  const float* csb = ctxsum + bh * DD;
#pragma unroll
  for (int E = 0; E < 4; ++E) {
    const float cse = csb[E * 16 + c];
#pragma unroll
    for (int jj = 0; jj < 4; ++jj) {
      const int row = r0 + w * 16 + sq * 4 + jj;
      out[((size_t)bh * NN + row) * DD + E * 16 + c] =
          (oacc[E][jj] + fac[jj] * cse) * oinv[jj];
    }
  }
}

extern "C" void kernel_launch(void* const* d_in, const int* in_sizes, int n_in,
                              void* d_out, int out_size, void* d_ws, size_t ws_size,
                              hipStream_t stream) {
  const float* Q    = (const float*)d_in[0];
  const float* K    = (const float*)d_in[1];
  const float* V    = (const float*)d_in[2];
  const float* mask = (const float*)d_in[3];
  const float* proj = (const float*)d_in[4];
  float* out = (float*)d_out;

  float* wsf = (float*)d_ws;
  float* stabk  = wsf;                          // 32
  float* ksum   = wsf + 32;                     // 8192
  float* kssum  = wsf + 8224;                   // 32
  float* Vs     = wsf + 8256;                   // 2048
  float* ctxsum = wsf + 10304;                  // 2048
  float* ksE    = wsf + 12352;                  // 8192
  unsigned short* projH = (unsigned short*)(wsf + 20544);   // 16384 shorts
  unsigned short* projL = (unsigned short*)(wsf + 28736);   // 16384 shorts
  unsigned short* ctxTH = (unsigned short*)(wsf + 36928);   // 524288 shorts
  unsigned short* ctxTL = (unsigned short*)(wsf + 299072);  // 524288 shorts
  float* ctxBig = wsf + 561216;  // PARTIAL: NCH*32*16384 = 8388608 fl (33.5MB)
                                 // fallback: 524288 fl (ctxE)

  const size_t need_partial = (size_t)(561216 + NCH * BH * MM * DD) * 4;
  const bool partial = ws_size >= need_partial;

  prep_kernel<<<64, 256, 0, stream>>>(proj, projH, projL, stabk, Vs, ctxsum, ksE);

  if (partial) {
    kside_kernel<true><<<dim3(NCH, BH), 256, 0, stream>>>(
        K, V, mask, projH, projL, stabk, ksE, ctxBig, Vs);
    fixup_kernel<NCH><<<dim3(8, BH), 256, 0, stream>>>(
        stabk, Vs, ksE, ctxBig, ksum, kssum, ctxsum, ctxTH, ctxTL);
  } else {
    hipMemsetAsync(ctxBig, 0, (size_t)MM * DD * BH * 4, stream);
    kside_kernel<false><<<dim3(NCH, BH), 256, 0, stream>>>(
        K, V, mask, projH, projL, stabk, ksE, ctxBig, Vs);
    fixup_kernel<1><<<dim3(8, BH), 256, 0, stream>>>(
        stabk, Vs, ksE, ctxBig, ksum, kssum, ctxsum, ctxTH, ctxTL);
  }

  out_kernel<<<dim3(64, BH), 256, 0, stream>>>(
      Q, projH, projL, ksum, ctxTH, ctxTL, kssum, ctxsum, out);
}